// Round 1
// baseline (6878.373 us; speedup 1.0000x reference)
//
#include <hip/hip_runtime.h>
#include <math.h>

#define BATCH 64
#define NREF  256
#define NPTS  2048
#define DIM   128
#define ITERS 100

// ---------- online logsumexp helpers (max-subtracted, stable for logits ~ -16000) ----------
__device__ __forceinline__ void online_step(float t, float& m, float& s) {
    float nm = fmaxf(m, t);
    s = s * __expf(m - nm) + __expf(t - nm);   // exp(-inf)=0 on first step
    m = nm;
}
__device__ __forceinline__ void online_combine(float& m, float& s, float mo, float so) {
    float nm = fmaxf(m, mo);
    s = s * __expf(m - nm) + so * __expf(mo - nm);
    m = nm;
}

// ---------- ref row norms: r2[i] = sum_k ref[i][k]^2 ----------
__global__ __launch_bounds__(256) void r2_kernel(const float* __restrict__ ref,
                                                 float* __restrict__ r2) {
    int i = threadIdx.x;  // 256 threads, one per ref row
    const float4* r4 = (const float4*)(ref + (size_t)i * DIM);
    float acc = 0.f;
#pragma unroll
    for (int k = 0; k < DIM / 4; ++k) {
        float4 a = r4[k];
        acc += a.x * a.x + a.y * a.y + a.z * a.z + a.w * a.w;
    }
    r2[i] = acc;
}

// ---------- C[b][i][j] = sqrt(max(r2_i + x2_bj - 2*dot(ref_i, X_bj), 0)) ----------
// grid: 64 b * 32 j-chunks (64 j each). 256 threads: lane jj owns column j,
// wave g owns i-range [g*64, g*64+64). X row lives in registers 16 floats at a
// time; ref accesses are wave-uniform -> scalar loads.
__global__ __launch_bounds__(256) void c_kernel(const float* __restrict__ X,
                                                const float* __restrict__ ref,
                                                const float* __restrict__ r2,
                                                float* __restrict__ C) {
    int b  = blockIdx.x >> 5;
    int jc = blockIdx.x & 31;
    int jj = threadIdx.x & 63;
    int g  = threadIdx.x >> 6;
    int j  = jc * 64 + jj;
    const float* xrow = X + ((size_t)b * NPTS + j) * DIM;

    float acc[64];
#pragma unroll
    for (int i = 0; i < 64; ++i) acc[i] = 0.f;
    float x2 = 0.f;

    for (int k0 = 0; k0 < DIM; k0 += 16) {
        float xv[16];
        const float4* xp = (const float4*)(xrow + k0);
#pragma unroll
        for (int q = 0; q < 4; ++q) {
            float4 t = xp[q];
            xv[q * 4 + 0] = t.x; xv[q * 4 + 1] = t.y;
            xv[q * 4 + 2] = t.z; xv[q * 4 + 3] = t.w;
        }
#pragma unroll
        for (int k = 0; k < 16; ++k) x2 = fmaf(xv[k], xv[k], x2);

        const float* rbase = ref + (size_t)(g * 64) * DIM + k0;
#pragma unroll
        for (int i = 0; i < 64; ++i) {
            const float* rr = rbase + (size_t)i * DIM;  // wave-uniform -> s_load
#pragma unroll
            for (int k = 0; k < 16; ++k) acc[i] = fmaf(rr[k], xv[k], acc[i]);
        }
    }

    float* crow = C + ((size_t)b * NREF + (size_t)g * 64) * NPTS + j;
#pragma unroll
    for (int i = 0; i < 64; ++i) {
        float sq = r2[g * 64 + i] + x2 - 2.f * acc[i];
        crow[(size_t)i * NPTS] = sqrtf(fmaxf(sq, 0.f));
    }
}

// ---------- u update: u[b][i] = eps*(log_wx - lse_j((v_j - C_ij)/eps)) ----------
// one wave per row (b,i); 4 rows per 256-thread block. Coalesced float4 row reads.
__global__ __launch_bounds__(256) void u_kernel(const float* __restrict__ C,
                                                const float* __restrict__ v,
                                                float* __restrict__ u,
                                                float log_wx, float inv_eps, float eps) {
    int row  = blockIdx.x * 4 + (threadIdx.x >> 6);   // b*256 + i
    int lane = threadIdx.x & 63;
    int b    = row >> 8;
    const float4* crow = (const float4*)(C + (size_t)row * NPTS);
    const float4* vrow = (const float4*)(v + (size_t)b * NPTS);

    float m0 = -INFINITY, m1 = -INFINITY, m2 = -INFINITY, m3 = -INFINITY;
    float s0 = 0.f, s1 = 0.f, s2 = 0.f, s3 = 0.f;
#pragma unroll
    for (int c = 0; c < 8; ++c) {
        int idx = c * 64 + lane;
        float4 cv = crow[idx];
        float4 vv = vrow[idx];
        online_step((vv.x - cv.x) * inv_eps, m0, s0);
        online_step((vv.y - cv.y) * inv_eps, m1, s1);
        online_step((vv.z - cv.z) * inv_eps, m2, s2);
        online_step((vv.w - cv.w) * inv_eps, m3, s3);
    }
    online_combine(m0, s0, m1, s1);
    online_combine(m2, s2, m3, s3);
    online_combine(m0, s0, m2, s2);
#pragma unroll
    for (int off = 1; off < 64; off <<= 1) {
        float mo = __shfl_xor(m0, off);
        float so = __shfl_xor(s0, off);
        online_combine(m0, s0, mo, so);
    }
    if (lane == 0) u[row] = eps * (log_wx - (m0 + __logf(s0)));
}

// ---------- v update: v[b][j] = eps*(log_wy - lse_i((u_i - C_ij)/eps)) ----------
// one thread per (b,j); column walk is coalesced across the wave. u reads are
// wave-uniform -> scalar loads. 4 independent online states break the dep chain.
__global__ __launch_bounds__(256) void v_kernel(const float* __restrict__ C,
                                                const float* __restrict__ u,
                                                float* __restrict__ vout,
                                                float log_wy, float inv_eps, float eps) {
    int gid = blockIdx.x * 256 + threadIdx.x;     // 0 .. 64*2048-1
    int b   = gid >> 11;
    int j   = gid & (NPTS - 1);
    const float* ccol = C + (size_t)b * NREF * NPTS + j;
    const float* ub   = u + (size_t)b * NREF;

    float m0 = -INFINITY, m1 = -INFINITY, m2 = -INFINITY, m3 = -INFINITY;
    float s0 = 0.f, s1 = 0.f, s2 = 0.f, s3 = 0.f;
    for (int i = 0; i < NREF; i += 4) {
        float c0 = ccol[(size_t)(i + 0) * NPTS];
        float c1 = ccol[(size_t)(i + 1) * NPTS];
        float c2 = ccol[(size_t)(i + 2) * NPTS];
        float c3 = ccol[(size_t)(i + 3) * NPTS];
        online_step((ub[i + 0] - c0) * inv_eps, m0, s0);
        online_step((ub[i + 1] - c1) * inv_eps, m1, s1);
        online_step((ub[i + 2] - c2) * inv_eps, m2, s2);
        online_step((ub[i + 3] - c3) * inv_eps, m3, s3);
    }
    online_combine(m0, s0, m1, s1);
    online_combine(m2, s2, m3, s3);
    online_combine(m0, s0, m2, s2);
    vout[gid] = eps * (log_wy - (m0 + __logf(s0)));
}

// ---------- epilogue: out[b][i][:] = (sum_j P_ij X_j)/(sum_j P_ij + 1e-8) - ref_i ----------
// P_ij = exp((u_i + v_j - C_ij)/eps)  (bounded <= ~1 at convergence; no max needed).
// block = (b, 8-row i-tile). Weights for the 8 rows staged in 64 KiB LDS.
__global__ __launch_bounds__(256) void out_kernel(const float* __restrict__ C,
                                                  const float* __restrict__ X,
                                                  const float* __restrict__ ref,
                                                  const float* __restrict__ u,
                                                  const float* __restrict__ v,
                                                  float* __restrict__ out,
                                                  float inv_eps) {
    __shared__ float w[8 * NPTS];   // exactly 64 KiB
    int b  = blockIdx.x >> 5;
    int it = blockIdx.x & 31;
    int i0 = it * 8;
    const float* Cb = C + ((size_t)b * NREF + i0) * NPTS;
    const float* vb = v + (size_t)b * NPTS;
    const float* ub = u + (size_t)b * NREF + i0;

    for (int idx = threadIdx.x; idx < 8 * NPTS; idx += 256) {
        int r  = idx >> 11;
        int jj = idx & (NPTS - 1);
        w[idx] = __expf((ub[r] + vb[jj] - Cb[(size_t)r * NPTS + jj]) * inv_eps);
    }
    __syncthreads();

    int r = threadIdx.x >> 5;   // 8 rows x 32 lanes
    int t = threadIdx.x & 31;

    // row denom: 32-lane tree over the 2048 weights of row r
    float part = 0.f;
#pragma unroll 8
    for (int k = 0; k < 64; ++k) part += w[r * NPTS + t + 32 * k];
#pragma unroll
    for (int off = 1; off < 32; off <<= 1) part += __shfl_xor(part, off);
    float dn = part + 1e-8f;

    // weighted sum of X rows; lane t owns float4 d-slot t (d = 4t..4t+3)
    const float4* X4 = (const float4*)(X + (size_t)b * NPTS * DIM);
    float ax = 0.f, ay = 0.f, az = 0.f, aw = 0.f;
    for (int j = 0; j < NPTS; j += 4) {
        float4 wv = *(const float4*)&w[r * NPTS + j];   // LDS broadcast per r-group
        float4 xa = X4[(size_t)(j + 0) * 32 + t];
        float4 xb = X4[(size_t)(j + 1) * 32 + t];
        float4 xc = X4[(size_t)(j + 2) * 32 + t];
        float4 xd = X4[(size_t)(j + 3) * 32 + t];
        ax = fmaf(wv.x, xa.x, ax); ay = fmaf(wv.x, xa.y, ay); az = fmaf(wv.x, xa.z, az); aw = fmaf(wv.x, xa.w, aw);
        ax = fmaf(wv.y, xb.x, ax); ay = fmaf(wv.y, xb.y, ay); az = fmaf(wv.y, xb.z, az); aw = fmaf(wv.y, xb.w, aw);
        ax = fmaf(wv.z, xc.x, ax); ay = fmaf(wv.z, xc.y, ay); az = fmaf(wv.z, xc.z, az); aw = fmaf(wv.z, xc.w, aw);
        ax = fmaf(wv.w, xd.x, ax); ay = fmaf(wv.w, xd.y, ay); az = fmaf(wv.w, xd.z, az); aw = fmaf(wv.w, xd.w, aw);
    }

    int i = i0 + r;
    float4 rf = ((const float4*)(ref + (size_t)i * DIM))[t];
    float4 o;
    o.x = ax / dn - rf.x;
    o.y = ay / dn - rf.y;
    o.z = az / dn - rf.z;
    o.w = aw / dn - rf.w;
    ((float4*)(out + ((size_t)b * NREF + i) * DIM))[t] = o;
}

extern "C" void kernel_launch(void* const* d_in, const int* in_sizes, int n_in,
                              void* d_out, int out_size, void* d_ws, size_t ws_size,
                              hipStream_t stream) {
    const float* X   = (const float*)d_in[0];   // (64, 2048, 128)
    const float* ref = (const float*)d_in[1];   // (256, 128)
    float* out = (float*)d_out;                 // (64, 256, 128)

    char* ws = (char*)d_ws;
    size_t coff = (size_t)BATCH * NREF * NPTS * sizeof(float);   // 134,217,728
    float* C  = (float*)ws;
    float* u  = (float*)(ws + coff);
    float* v  = (float*)(ws + coff + (size_t)BATCH * NREF * sizeof(float));
    float* r2 = (float*)(ws + coff + (size_t)BATCH * NREF * sizeof(float)
                              + (size_t)BATCH * NPTS * sizeof(float));

    const float eps     = 0.001f;
    const float inv_eps = 1.0f / eps;
    const float log_wx  = (float)log(1.0 / (double)NREF + 1e-8);
    const float log_wy  = (float)log(1.0 / (double)NPTS + 1e-8);

    hipMemsetAsync(v, 0, (size_t)BATCH * NPTS * sizeof(float), stream);  // v0 = 0

    r2_kernel<<<1, 256, 0, stream>>>(ref, r2);
    c_kernel<<<BATCH * 32, 256, 0, stream>>>(X, ref, r2, C);

    for (int itn = 0; itn < ITERS; ++itn) {
        u_kernel<<<BATCH * NREF / 4, 256, 0, stream>>>(C, v, u, log_wx, inv_eps, eps);
        v_kernel<<<BATCH * NPTS / 256, 256, 0, stream>>>(C, u, v, log_wy, inv_eps, eps);
    }

    out_kernel<<<BATCH * 32, 256, 0, stream>>>(C, X, ref, u, v, out, inv_eps);
}

// Round 2
// 5486.667 us; speedup vs baseline: 1.2537x; 1.2537x over previous
//
#include <hip/hip_runtime.h>
#include <math.h>

#define BATCH 64
#define NREF  256
#define NPTS  2048
#define DIM   128
#define ITERS 100
#define INV_EPS 1000.0f

// All potentials kept in SCALED (logit) domain: u' = u/eps, v' = v/eps, C' = C/eps.
// Updates: u' = log_wx - LSE_j(v'_j - C'_ij); v' = log_wy - LSE_i(u'_i - C'_ij).
// Epilogue weights: P = exp(u' + v' - C').

// ---------- branchless single-exp online LSE step ----------
// exactly one of (m-nm),(t-nm) is 0, the other is -|m-t|, so their sum is -|m-t|.
__device__ __forceinline__ void lse_step(float t, float& m, float& s) {
    float nm = fmaxf(m, t);
    float e  = __expf(m + t - 2.0f * nm);      // exp(-|m-t|); 0 when m==-inf
    float s1 = fmaf(s, e, 1.0f);               // case t > m (new max)
    float s2 = s + e;                          // case t <= m
    s = (t > m) ? s1 : s2;
    m = nm;
}
__device__ __forceinline__ void lse_combine(float& m, float& s, float mo, float so) {
    float nm = fmaxf(m, mo);
    s = s * __expf(m - nm) + so * __expf(mo - nm);
    m = nm;
}

// ---------- ref row norms ----------
__global__ __launch_bounds__(256) void r2_kernel(const float* __restrict__ ref,
                                                 float* __restrict__ r2) {
    int i = threadIdx.x;
    const float4* r4 = (const float4*)(ref + (size_t)i * DIM);
    float acc = 0.f;
#pragma unroll
    for (int k = 0; k < DIM / 4; ++k) {
        float4 a = r4[k];
        acc += a.x * a.x + a.y * a.y + a.z * a.z + a.w * a.w;
    }
    r2[i] = acc;
}

// ---------- C'[b][i][j] = sqrt(max(r2_i + x2_bj - 2*dot(ref_i, X_bj), 0)) * INV_EPS ----------
// Block: 256 threads, one j per thread; i-tile of 64 shared by the WHOLE block so
// ref/r2 addresses are block-uniform -> scalar s_load (kills last round's 1024
// redundant per-lane vector loads per chunk).
__global__ __launch_bounds__(256) void c_kernel(const float* __restrict__ X,
                                                const float* __restrict__ ref,
                                                const float* __restrict__ r2,
                                                float* __restrict__ C) {
    int b  = blockIdx.x >> 5;
    int it = (blockIdx.x >> 3) & 3;
    int jc = blockIdx.x & 7;
    int j  = jc * 256 + threadIdx.x;
    int i0 = it * 64;
    const float* xrow = X + ((size_t)b * NPTS + j) * DIM;

    float acc[64];
#pragma unroll
    for (int i = 0; i < 64; ++i) acc[i] = 0.f;
    float x2 = 0.f;

    for (int k0 = 0; k0 < DIM; k0 += 16) {
        float xv[16];
        const float4* xp = (const float4*)(xrow + k0);
#pragma unroll
        for (int q = 0; q < 4; ++q) {
            float4 t = xp[q];
            xv[q * 4 + 0] = t.x; xv[q * 4 + 1] = t.y;
            xv[q * 4 + 2] = t.z; xv[q * 4 + 3] = t.w;
        }
#pragma unroll
        for (int k = 0; k < 16; ++k) x2 = fmaf(xv[k], xv[k], x2);

        const float* rbase = ref + (size_t)i0 * DIM + k0;   // block-uniform
#pragma unroll
        for (int i = 0; i < 64; ++i) {
            const float* rr = rbase + (size_t)i * DIM;      // uniform -> s_load
#pragma unroll
            for (int k = 0; k < 16; ++k) acc[i] = fmaf(rr[k], xv[k], acc[i]);
        }
    }

    float* cbase = C + ((size_t)b * NREF + i0) * NPTS + j;
#pragma unroll
    for (int i = 0; i < 64; ++i) {
        float sq = r2[i0 + i] + x2 - 2.f * acc[i];
        cbase[(size_t)i * NPTS] = sqrtf(fmaxf(sq, 0.f)) * INV_EPS;
    }
}

// ---------- u' update: one wave per row; row cached in 32 VGPRs; two-pass, 1 exp/elem ----------
__global__ __launch_bounds__(256) void u_kernel(const float* __restrict__ C,
                                                const float* __restrict__ v,
                                                float* __restrict__ u,
                                                float log_wx) {
    int row  = blockIdx.x * 4 + (threadIdx.x >> 6);   // b*256 + i
    int lane = threadIdx.x & 63;
    int b    = row >> 8;
    const float4* crow = (const float4*)(C + (size_t)row * NPTS);
    const float4* vrow = (const float4*)(v + (size_t)b * NPTS);

    float4 t[8];
    float m = -INFINITY;
#pragma unroll
    for (int c = 0; c < 8; ++c) {
        float4 cv = crow[c * 64 + lane];
        float4 vv = vrow[c * 64 + lane];
        float4 tt;
        tt.x = vv.x - cv.x; tt.y = vv.y - cv.y;
        tt.z = vv.z - cv.z; tt.w = vv.w - cv.w;
        t[c] = tt;
        m = fmaxf(m, fmaxf(fmaxf(tt.x, tt.y), fmaxf(tt.z, tt.w)));
    }
#pragma unroll
    for (int off = 1; off < 64; off <<= 1) m = fmaxf(m, __shfl_xor(m, off));

    float s0 = 0.f, s1 = 0.f, s2 = 0.f, s3 = 0.f;
#pragma unroll
    for (int c = 0; c < 8; ++c) {
        s0 += __expf(t[c].x - m);
        s1 += __expf(t[c].y - m);
        s2 += __expf(t[c].z - m);
        s3 += __expf(t[c].w - m);
    }
    float s = (s0 + s1) + (s2 + s3);
#pragma unroll
    for (int off = 1; off < 64; off <<= 1) s += __shfl_xor(s, off);

    if (lane == 0) u[row] = log_wx - (m + __logf(s));
}

// ---------- v' update: 2 columns per thread, float2 loads, single-exp online ----------
__global__ __launch_bounds__(256) void v_kernel(const float* __restrict__ C,
                                                const float* __restrict__ u,
                                                float* __restrict__ vout,
                                                float log_wy) {
    int gid = blockIdx.x * 256 + threadIdx.x;          // 0 .. 64*1024-1
    int b   = __builtin_amdgcn_readfirstlane(gid >> 10);
    int jp  = gid & 1023;                              // float2 column pair index
    const float2* ccol = (const float2*)(C + (size_t)b * NREF * NPTS) + jp;
    const float* ub    = u + (size_t)b * NREF;         // scalar base -> s_load

    float m00 = -INFINITY, s00 = 0.f, m01 = -INFINITY, s01 = 0.f;  // col j
    float m10 = -INFINITY, s10 = 0.f, m11 = -INFINITY, s11 = 0.f;  // col j+1
#pragma unroll 4
    for (int i = 0; i < NREF; i += 2) {
        float2 c0 = ccol[(size_t)(i + 0) * (NPTS / 2)];
        float2 c1 = ccol[(size_t)(i + 1) * (NPTS / 2)];
        float u0 = ub[i + 0];
        float u1 = ub[i + 1];
        lse_step(u0 - c0.x, m00, s00);
        lse_step(u1 - c1.x, m01, s01);
        lse_step(u0 - c0.y, m10, s10);
        lse_step(u1 - c1.y, m11, s11);
    }
    lse_combine(m00, s00, m01, s01);
    lse_combine(m10, s10, m11, s11);

    float2 out;
    out.x = log_wy - (m00 + __logf(s00));
    out.y = log_wy - (m10 + __logf(s10));
    ((float2*)(vout + (size_t)b * NPTS))[jp] = out;
}

// ---------- epilogue: out[b][i][:] = (sum_j P_ij X_j)/(sum_j P_ij + 1e-8) - ref_i ----------
// P = exp(u' + v' - C'), all scaled-domain, each term <= ~1 at convergence.
__global__ __launch_bounds__(256) void out_kernel(const float* __restrict__ C,
                                                  const float* __restrict__ X,
                                                  const float* __restrict__ ref,
                                                  const float* __restrict__ u,
                                                  const float* __restrict__ v,
                                                  float* __restrict__ out) {
    __shared__ float w[8 * NPTS];   // 64 KiB
    int b  = blockIdx.x >> 5;
    int it = blockIdx.x & 31;
    int i0 = it * 8;
    const float* Cb = C + ((size_t)b * NREF + i0) * NPTS;
    const float* vb = v + (size_t)b * NPTS;
    const float* ub = u + (size_t)b * NREF + i0;

    for (int idx = threadIdx.x; idx < 8 * NPTS; idx += 256) {
        int r  = idx >> 11;
        int jj = idx & (NPTS - 1);
        w[idx] = __expf(ub[r] + vb[jj] - Cb[(size_t)r * NPTS + jj]);
    }
    __syncthreads();

    int r = threadIdx.x >> 5;
    int t = threadIdx.x & 31;

    float part = 0.f;
#pragma unroll 8
    for (int k = 0; k < 64; ++k) part += w[r * NPTS + t + 32 * k];
#pragma unroll
    for (int off = 1; off < 32; off <<= 1) part += __shfl_xor(part, off);
    float dn = part + 1e-8f;

    const float4* X4 = (const float4*)(X + (size_t)b * NPTS * DIM);
    float ax = 0.f, ay = 0.f, az = 0.f, aw = 0.f;
    for (int j = 0; j < NPTS; j += 4) {
        float4 wv = *(const float4*)&w[r * NPTS + j];
        float4 xa = X4[(size_t)(j + 0) * 32 + t];
        float4 xb = X4[(size_t)(j + 1) * 32 + t];
        float4 xc = X4[(size_t)(j + 2) * 32 + t];
        float4 xd = X4[(size_t)(j + 3) * 32 + t];
        ax = fmaf(wv.x, xa.x, ax); ay = fmaf(wv.x, xa.y, ay); az = fmaf(wv.x, xa.z, az); aw = fmaf(wv.x, xa.w, aw);
        ax = fmaf(wv.y, xb.x, ax); ay = fmaf(wv.y, xb.y, ay); az = fmaf(wv.y, xb.z, az); aw = fmaf(wv.y, xb.w, aw);
        ax = fmaf(wv.z, xc.x, ax); ay = fmaf(wv.z, xc.y, ay); az = fmaf(wv.z, xc.z, az); aw = fmaf(wv.z, xc.w, aw);
        ax = fmaf(wv.w, xd.x, ax); ay = fmaf(wv.w, xd.y, ay); az = fmaf(wv.w, xd.z, az); aw = fmaf(wv.w, xd.w, aw);
    }

    int i = i0 + r;
    float4 rf = ((const float4*)(ref + (size_t)i * DIM))[t];
    float4 o;
    o.x = ax / dn - rf.x;
    o.y = ay / dn - rf.y;
    o.z = az / dn - rf.z;
    o.w = aw / dn - rf.w;
    ((float4*)(out + ((size_t)b * NREF + i) * DIM))[t] = o;
}

extern "C" void kernel_launch(void* const* d_in, const int* in_sizes, int n_in,
                              void* d_out, int out_size, void* d_ws, size_t ws_size,
                              hipStream_t stream) {
    const float* X   = (const float*)d_in[0];
    const float* ref = (const float*)d_in[1];
    float* out = (float*)d_out;

    char* ws = (char*)d_ws;
    size_t coff = (size_t)BATCH * NREF * NPTS * sizeof(float);
    float* C  = (float*)ws;
    float* u  = (float*)(ws + coff);
    float* v  = (float*)(ws + coff + (size_t)BATCH * NREF * sizeof(float));
    float* r2 = (float*)(ws + coff + (size_t)BATCH * NREF * sizeof(float)
                              + (size_t)BATCH * NPTS * sizeof(float));

    const float log_wx = (float)log(1.0 / (double)NREF + 1e-8);
    const float log_wy = (float)log(1.0 / (double)NPTS + 1e-8);

    hipMemsetAsync(v, 0, (size_t)BATCH * NPTS * sizeof(float), stream);

    r2_kernel<<<1, 256, 0, stream>>>(ref, r2);
    c_kernel<<<BATCH * 32, 256, 0, stream>>>(X, ref, r2, C);

    for (int itn = 0; itn < ITERS; ++itn) {
        u_kernel<<<BATCH * NREF / 4, 256, 0, stream>>>(C, v, u, log_wx);
        v_kernel<<<BATCH * NPTS / 512, 256, 0, stream>>>(C, u, v, log_wy);
    }

    out_kernel<<<BATCH * 32, 256, 0, stream>>>(C, X, ref, u, v, out);
}

// Round 3
// 4957.083 us; speedup vs baseline: 1.3876x; 1.1068x over previous
//
#include <hip/hip_runtime.h>
#include <math.h>

#define BATCH 64
#define NREF  256
#define NPTS  2048
#define DIM   128
#define ITERS 100
#define INV_EPS 1000.0f

// Scaled (logit) domain throughout: u' = u/eps, v' = v/eps, C' = C/eps.

// ---------- branchless single-exp online LSE step ----------
__device__ __forceinline__ void lse_step(float t, float& m, float& s) {
    float nm = fmaxf(m, t);
    float e  = __expf(m + t - 2.0f * nm);      // exp(-|m-t|); 0 when m==-inf
    float s1 = fmaf(s, e, 1.0f);               // t is new max
    float s2 = s + e;                          // t <= m
    s = (t > m) ? s1 : s2;
    m = nm;
}
__device__ __forceinline__ void lse_combine(float& m, float& s, float mo, float so) {
    float nm = fmaxf(m, mo);
    s = s * __expf(m - nm) + so * __expf(mo - nm);
    m = nm;
}

// ---------- ref row norms ----------
__global__ __launch_bounds__(256) void r2_kernel(const float* __restrict__ ref,
                                                 float* __restrict__ r2) {
    int i = threadIdx.x;
    const float4* r4 = (const float4*)(ref + (size_t)i * DIM);
    float acc = 0.f;
#pragma unroll
    for (int k = 0; k < DIM / 4; ++k) {
        float4 a = r4[k];
        acc += a.x * a.x + a.y * a.y + a.z * a.z + a.w * a.w;
    }
    r2[i] = acc;
}

// ---------- C'[b][i][j] = sqrt(max(r2_i + x2_bj - 2*dot(ref_i, X_bj), 0)) * INV_EPS ----------
__global__ __launch_bounds__(256) void c_kernel(const float* __restrict__ X,
                                                const float* __restrict__ ref,
                                                const float* __restrict__ r2,
                                                float* __restrict__ C) {
    int b  = blockIdx.x >> 5;
    int it = (blockIdx.x >> 3) & 3;
    int jc = blockIdx.x & 7;
    int j  = jc * 256 + threadIdx.x;
    int i0 = it * 64;
    const float* xrow = X + ((size_t)b * NPTS + j) * DIM;

    float acc[64];
#pragma unroll
    for (int i = 0; i < 64; ++i) acc[i] = 0.f;
    float x2 = 0.f;

    for (int k0 = 0; k0 < DIM; k0 += 16) {
        float xv[16];
        const float4* xp = (const float4*)(xrow + k0);
#pragma unroll
        for (int q = 0; q < 4; ++q) {
            float4 t = xp[q];
            xv[q * 4 + 0] = t.x; xv[q * 4 + 1] = t.y;
            xv[q * 4 + 2] = t.z; xv[q * 4 + 3] = t.w;
        }
#pragma unroll
        for (int k = 0; k < 16; ++k) x2 = fmaf(xv[k], xv[k], x2);

        const float* rbase = ref + (size_t)i0 * DIM + k0;   // block-uniform -> s_load
#pragma unroll
        for (int i = 0; i < 64; ++i) {
            const float* rr = rbase + (size_t)i * DIM;
#pragma unroll
            for (int k = 0; k < 16; ++k) acc[i] = fmaf(rr[k], xv[k], acc[i]);
        }
    }

    float* cbase = C + ((size_t)b * NREF + i0) * NPTS + j;
#pragma unroll
    for (int i = 0; i < 64; ++i) {
        float sq = r2[i0 + i] + x2 - 2.f * acc[i];
        cbase[(size_t)i * NPTS] = sqrtf(fmaxf(sq, 0.f)) * INV_EPS;
    }
}

// ---------- u' update: one wave per row; two-pass, 1 exp/elem ----------
__global__ __launch_bounds__(256) void u_kernel(const float* __restrict__ C,
                                                const float* __restrict__ v,
                                                float* __restrict__ u,
                                                float log_wx) {
    int row  = blockIdx.x * 4 + (threadIdx.x >> 6);   // b*256 + i
    int lane = threadIdx.x & 63;
    int b    = row >> 8;
    const float4* crow = (const float4*)(C + (size_t)row * NPTS);
    const float4* vrow = (const float4*)(v + (size_t)b * NPTS);

    float4 t[8];
    float m = -INFINITY;
#pragma unroll
    for (int c = 0; c < 8; ++c) {
        float4 cv = crow[c * 64 + lane];
        float4 vv = vrow[c * 64 + lane];
        float4 tt;
        tt.x = vv.x - cv.x; tt.y = vv.y - cv.y;
        tt.z = vv.z - cv.z; tt.w = vv.w - cv.w;
        t[c] = tt;
        m = fmaxf(m, fmaxf(fmaxf(tt.x, tt.y), fmaxf(tt.z, tt.w)));
    }
#pragma unroll
    for (int off = 1; off < 64; off <<= 1) m = fmaxf(m, __shfl_xor(m, off));

    float s0 = 0.f, s1 = 0.f, s2 = 0.f, s3 = 0.f;
#pragma unroll
    for (int c = 0; c < 8; ++c) {
        s0 += __expf(t[c].x - m);
        s1 += __expf(t[c].y - m);
        s2 += __expf(t[c].z - m);
        s3 += __expf(t[c].w - m);
    }
    float s = (s0 + s1) + (s2 + s3);
#pragma unroll
    for (int off = 1; off < 64; off <<= 1) s += __shfl_xor(s, off);

    if (lane == 0) u[row] = log_wx - (m + __logf(s));
}

// ---------- v' update: block = 64 columns x 4 i-groups of 64; LDS combine ----------
// 2048 blocks -> 8 blocks/CU (full occupancy); per-thread chain 64 deep.
__global__ __launch_bounds__(256) void v_kernel(const float* __restrict__ C,
                                                const float* __restrict__ u,
                                                float* __restrict__ vout,
                                                float log_wy) {
    __shared__ float sm[4][64];
    __shared__ float ss[4][64];
    int b  = blockIdx.x >> 5;
    int jc = blockIdx.x & 31;
    int jj = threadIdx.x & 63;
    int g  = threadIdx.x >> 6;          // wave index -> wave-uniform
    int j  = jc * 64 + jj;
    const float* cg = C + ((size_t)b * NREF + (size_t)g * 64) * NPTS + j;
    const float* ub = u + (size_t)b * NREF + g * 64;   // wave-uniform -> s_load

    float m0 = -INFINITY, s0 = 0.f, m1 = -INFINITY, s1 = 0.f;
#pragma unroll 8
    for (int i = 0; i < 64; i += 2) {
        float c0 = cg[(size_t)(i + 0) * NPTS];
        float c1 = cg[(size_t)(i + 1) * NPTS];
        lse_step(ub[i + 0] - c0, m0, s0);
        lse_step(ub[i + 1] - c1, m1, s1);
    }
    lse_combine(m0, s0, m1, s1);
    sm[g][jj] = m0; ss[g][jj] = s0;
    __syncthreads();
    if (g == 0) {
        float m = m0, s = s0;
#pragma unroll
        for (int q = 1; q < 4; ++q) lse_combine(m, s, sm[q][jj], ss[q][jj]);
        vout[(size_t)b * NPTS + j] = log_wy - (m + __logf(s));
    }
}

// ---------- epilogue v3: GEMM-style register tiling ----------
// block = (b, 32-row i-tile), 512 blocks. Loops all 2048 j in 32-wide tiles:
// X-tile (16KB) + w-tile (4KB) in LDS; X read from global ONCE per block.
// Thread (g = t>>5 row-group of 4 rows, s = t&31 d-slot): acc = 4 x float4.
__global__ __launch_bounds__(256) void out_kernel(const float* __restrict__ C,
                                                  const float* __restrict__ X,
                                                  const float* __restrict__ ref,
                                                  const float* __restrict__ u,
                                                  const float* __restrict__ v,
                                                  float* __restrict__ out) {
    __shared__ float wt[32 * 32];       // [row_local][jj]  4 KB
    __shared__ float xt[32 * DIM];      // [jj][d]         16 KB
    int b  = blockIdx.x >> 3;
    int it = blockIdx.x & 7;
    int i0 = it * 32;
    int t  = threadIdx.x;
    int s  = t & 31;                    // d-slot (float4 at d = 4s)
    int g  = t >> 5;                    // rows i0 + g*4 .. +3

    const float* Cb = C + ((size_t)b * NREF + i0) * NPTS;
    const float* vb = v + (size_t)b * NPTS;
    const float* ub = u + (size_t)b * NREF + i0;

    float4 acc[4];
    float wsum[4];
#pragma unroll
    for (int r = 0; r < 4; ++r) { acc[r] = make_float4(0.f, 0.f, 0.f, 0.f); wsum[r] = 0.f; }

    for (int j0 = 0; j0 < NPTS; j0 += 32) {
        // stage w-tile: 32 rows x 32 jj (4 per thread, coalesced C reads)
#pragma unroll
        for (int k = 0; k < 4; ++k) {
            int widx = t + 256 * k;
            int r    = widx >> 5;
            int jj   = widx & 31;
            wt[widx] = __expf(ub[r] + vb[j0 + jj] - Cb[(size_t)r * NPTS + j0 + jj]);
        }
        // stage X-tile: 32 rows x 128 d = 1024 float4 (4 per thread)
        const float4* Xb4 = (const float4*)(X + ((size_t)b * NPTS + j0) * DIM);
#pragma unroll
        for (int k = 0; k < 4; ++k) {
            int idx = t + 256 * k;
            ((float4*)xt)[idx] = Xb4[idx];
        }
        __syncthreads();

        const float4* xt4 = (const float4*)xt;
#pragma unroll 2
        for (int jj = 0; jj < 32; jj += 4) {
            float4 xv0 = xt4[(jj + 0) * 32 + s];
            float4 xv1 = xt4[(jj + 1) * 32 + s];
            float4 xv2 = xt4[(jj + 2) * 32 + s];
            float4 xv3 = xt4[(jj + 3) * 32 + s];
#pragma unroll
            for (int r = 0; r < 4; ++r) {
                float4 w4 = *(const float4*)&wt[(g * 4 + r) * 32 + jj];
                acc[r].x = fmaf(w4.x, xv0.x, acc[r].x); acc[r].y = fmaf(w4.x, xv0.y, acc[r].y);
                acc[r].z = fmaf(w4.x, xv0.z, acc[r].z); acc[r].w = fmaf(w4.x, xv0.w, acc[r].w);
                acc[r].x = fmaf(w4.y, xv1.x, acc[r].x); acc[r].y = fmaf(w4.y, xv1.y, acc[r].y);
                acc[r].z = fmaf(w4.y, xv1.z, acc[r].z); acc[r].w = fmaf(w4.y, xv1.w, acc[r].w);
                acc[r].x = fmaf(w4.z, xv2.x, acc[r].x); acc[r].y = fmaf(w4.z, xv2.y, acc[r].y);
                acc[r].z = fmaf(w4.z, xv2.z, acc[r].z); acc[r].w = fmaf(w4.z, xv2.w, acc[r].w);
                acc[r].x = fmaf(w4.w, xv3.x, acc[r].x); acc[r].y = fmaf(w4.w, xv3.y, acc[r].y);
                acc[r].z = fmaf(w4.w, xv3.z, acc[r].z); acc[r].w = fmaf(w4.w, xv3.w, acc[r].w);
                wsum[r] += (w4.x + w4.y) + (w4.z + w4.w);
            }
        }
        __syncthreads();
    }

#pragma unroll
    for (int r = 0; r < 4; ++r) {
        int i = i0 + g * 4 + r;
        float dn = wsum[r] + 1e-8f;
        float inv = 1.0f / dn;
        float4 rf = ((const float4*)(ref + (size_t)i * DIM))[s];
        float4 o;
        o.x = acc[r].x * inv - rf.x;
        o.y = acc[r].y * inv - rf.y;
        o.z = acc[r].z * inv - rf.z;
        o.w = acc[r].w * inv - rf.w;
        ((float4*)(out + ((size_t)b * NREF + i) * DIM))[s] = o;
    }
}

extern "C" void kernel_launch(void* const* d_in, const int* in_sizes, int n_in,
                              void* d_out, int out_size, void* d_ws, size_t ws_size,
                              hipStream_t stream) {
    const float* X   = (const float*)d_in[0];
    const float* ref = (const float*)d_in[1];
    float* out = (float*)d_out;

    char* ws = (char*)d_ws;
    size_t coff = (size_t)BATCH * NREF * NPTS * sizeof(float);
    float* C  = (float*)ws;
    float* u  = (float*)(ws + coff);
    float* v  = (float*)(ws + coff + (size_t)BATCH * NREF * sizeof(float));
    float* r2 = (float*)(ws + coff + (size_t)BATCH * NREF * sizeof(float)
                              + (size_t)BATCH * NPTS * sizeof(float));

    const float log_wx = (float)log(1.0 / (double)NREF + 1e-8);
    const float log_wy = (float)log(1.0 / (double)NPTS + 1e-8);

    hipMemsetAsync(v, 0, (size_t)BATCH * NPTS * sizeof(float), stream);

    r2_kernel<<<1, 256, 0, stream>>>(ref, r2);
    c_kernel<<<BATCH * 32, 256, 0, stream>>>(X, ref, r2, C);

    for (int itn = 0; itn < ITERS; ++itn) {
        u_kernel<<<BATCH * NREF / 4, 256, 0, stream>>>(C, v, u, log_wx);
        v_kernel<<<BATCH * 32, 256, 0, stream>>>(C, u, v, log_wy);
    }

    out_kernel<<<BATCH * 8, 256, 0, stream>>>(C, X, ref, u, v, out);
}